// Round 1
// baseline (847.539 us; speedup 1.0000x reference)
//
#include <hip/hip_runtime.h>
#include <hip/hip_bf16.h>

typedef __attribute__((ext_vector_type(8))) short bf16x8;
typedef __attribute__((ext_vector_type(4))) float f32x4;
typedef __hip_bfloat16 bf16_t;

#define D_MODEL 1024
#define NHEADS  16
#define DK      64
#define TSEQ    2048
#define BATCH   4
#define MTOK    (BATCH*TSEQ)   // 8192

// ---------------- fp32 -> bf16 elementwise convert (x) ----------------
__global__ __launch_bounds__(256) void convert_x_kernel(const float* __restrict__ x,
                                                        bf16_t* __restrict__ out, int n4) {
    int i = blockIdx.x * 256 + threadIdx.x;
    if (i >= n4) return;
    float4 v = reinterpret_cast<const float4*>(x)[i];
    union { bf16_t h[4]; uint2 u; } p;
    p.h[0] = __float2bfloat16(v.x);
    p.h[1] = __float2bfloat16(v.y);
    p.h[2] = __float2bfloat16(v.z);
    p.h[3] = __float2bfloat16(v.w);
    reinterpret_cast<uint2*>(out)[i] = p.u;
}

// ------------- transpose + convert weights: Wt[n][k] = W[k][n] -------------
__global__ __launch_bounds__(256) void transpose_w_kernel(
    const float* __restrict__ w0, const float* __restrict__ w1,
    const float* __restrict__ w2, const float* __restrict__ w3,
    bf16_t* __restrict__ o0, bf16_t* __restrict__ o1,
    bf16_t* __restrict__ o2, bf16_t* __restrict__ o3) {
    const float* w = (blockIdx.z == 0) ? w0 : (blockIdx.z == 1) ? w1 : (blockIdx.z == 2) ? w2 : w3;
    bf16_t* o = (blockIdx.z == 0) ? o0 : (blockIdx.z == 1) ? o1 : (blockIdx.z == 2) ? o2 : o3;
    __shared__ float tile[32][33];
    int tx = threadIdx.x, ty = threadIdx.y;     // block (32,8)
    int bx = blockIdx.x * 32;                   // k tile
    int by = blockIdx.y * 32;                   // n tile
    #pragma unroll
    for (int i = 0; i < 4; ++i)
        tile[ty + i*8][tx] = w[(bx + ty + i*8) * D_MODEL + by + tx];
    __syncthreads();
    #pragma unroll
    for (int i = 0; i < 4; ++i)
        o[(by + ty + i*8) * D_MODEL + bx + tx] = __float2bfloat16(tile[tx][ty + i*8]);
}

// ---------------- GEMM: C[M][N] = A[M][K] * Bt[N][K]^T + bias[n] ----------------
// MODE 0: fp32 plain row-major out
// MODE 1: bf16 out remapped to [B,H,T,dk]   (Q,K)
// MODE 2: bf16 out remapped to [B,H,dk,T]   (V transposed)
template<int MODE>
__global__ __launch_bounds__(256) void gemm_bf16_kernel(
    const bf16_t* __restrict__ A, const bf16_t* __restrict__ Bt,
    const float* __restrict__ bias, void* __restrict__ C,
    int M, int N, int K) {
    const int tid = threadIdx.x;
    const int wave = tid >> 6, lane = tid & 63;
    const int wm = wave >> 1, wn = wave & 1;          // 2x2 waves -> 128x128 tile
    const int m0 = blockIdx.y * 128 + wm * 64;
    const int n0 = blockIdx.x * 128 + wn * 64;
    const int lr = lane & 15, lg = lane >> 4;

    f32x4 acc[4][4] = {};
    for (int k0 = 0; k0 < K; k0 += 32) {
        bf16x8 a[4], b[4];
        #pragma unroll
        for (int mi = 0; mi < 4; ++mi)
            a[mi] = *reinterpret_cast<const bf16x8*>(&A[(size_t)(m0 + mi*16 + lr) * K + k0 + lg*8]);
        #pragma unroll
        for (int ni = 0; ni < 4; ++ni)
            b[ni] = *reinterpret_cast<const bf16x8*>(&Bt[(size_t)(n0 + ni*16 + lr) * K + k0 + lg*8]);
        #pragma unroll
        for (int mi = 0; mi < 4; ++mi)
            #pragma unroll
            for (int ni = 0; ni < 4; ++ni)
                acc[mi][ni] = __builtin_amdgcn_mfma_f32_16x16x32_bf16(a[mi], b[ni], acc[mi][ni], 0, 0, 0);
    }
    // epilogue
    #pragma unroll
    for (int mi = 0; mi < 4; ++mi) {
        #pragma unroll
        for (int ni = 0; ni < 4; ++ni) {
            int col = n0 + ni*16 + lr;
            float bv = bias[col];
            #pragma unroll
            for (int r = 0; r < 4; ++r) {
                int row = m0 + mi*16 + lg*4 + r;
                float val = acc[mi][ni][r] + bv;
                if (MODE == 0) {
                    reinterpret_cast<float*>(C)[(size_t)row * N + col] = val;
                } else if (MODE == 1) {
                    // row=(b,t) col=(h,d) -> [((b*16+h)*2048+t)*64+d]
                    size_t idx = (((size_t)(row >> 11) * NHEADS + (col >> 6)) * TSEQ + (row & 2047)) * DK + (col & 63);
                    reinterpret_cast<bf16_t*>(C)[idx] = __float2bfloat16(val);
                } else {
                    // [((b*16+h)*64+d)*2048+t]
                    size_t idx = (((size_t)(row >> 11) * NHEADS + (col >> 6)) * DK + (col & 63)) * TSEQ + (row & 2047);
                    reinterpret_cast<bf16_t*>(C)[idx] = __float2bfloat16(val);
                }
            }
        }
    }
}

// ---------------- Flash attention: per (qblock, b*h) ----------------
// Q,K: [BH][T][dk] bf16 ; Vt: [BH][dk][T] bf16 ; Y out: [B][T][H][dk] bf16
__global__ __launch_bounds__(256) void attn_kernel(
    const bf16_t* __restrict__ Q, const bf16_t* __restrict__ K,
    const bf16_t* __restrict__ Vt, bf16_t* __restrict__ Y) {
    const int qb = blockIdx.x;       // q-tile of 64 rows
    const int bh = blockIdx.y;       // b*16+h
    const int tid = threadIdx.x;
    const int wave = tid >> 6, lane = tid & 63;
    const int lr = lane & 15, lg = lane >> 4;
    const int q0 = qb * 64 + wave * 16;          // this wave's 16 q rows

    const bf16_t* Qh = Q + (size_t)bh * TSEQ * DK;
    const bf16_t* Kh = K + (size_t)bh * TSEQ * DK;
    const bf16_t* Vh = Vt + (size_t)bh * DK * TSEQ;

    bf16x8 qf[2];
    #pragma unroll
    for (int kk = 0; kk < 2; ++kk)
        qf[kk] = *reinterpret_cast<const bf16x8*>(&Qh[(size_t)(q0 + lr) * DK + kk*32 + lg*8]);

    f32x4 o[4] = {};
    float mrun[4], lrun[4];
    #pragma unroll
    for (int r = 0; r < 4; ++r) { mrun[r] = -__builtin_inff(); lrun[r] = 0.f; }

    __shared__ bf16_t plds[4][16][64];
    const float scale = 0.125f;

    for (int kt = 0; kt <= qb; ++kt) {
        // ---- S = Q K^T ----
        f32x4 s[4] = {};
        #pragma unroll
        for (int kk = 0; kk < 2; ++kk) {
            #pragma unroll
            for (int fn = 0; fn < 4; ++fn) {
                bf16x8 kb = *reinterpret_cast<const bf16x8*>(
                    &Kh[(size_t)(kt*64 + fn*16 + lr) * DK + kk*32 + lg*8]);
                s[fn] = __builtin_amdgcn_mfma_f32_16x16x32_bf16(qf[kk], kb, s[fn], 0, 0, 0);
            }
        }
        // ---- scale + causal mask (only diagonal tile needs mask) ----
        const bool diag = (kt == qb);
        #pragma unroll
        for (int fn = 0; fn < 4; ++fn) {
            int col = kt*64 + fn*16 + lr;
            #pragma unroll
            for (int r = 0; r < 4; ++r) {
                float v = s[fn][r] * scale;
                int row = q0 + lg*4 + r;
                if (diag && col > row) v = -__builtin_inff();
                s[fn][r] = v;
            }
        }
        // ---- row max over tile ----
        float tmax[4];
        #pragma unroll
        for (int r = 0; r < 4; ++r)
            tmax[r] = fmaxf(fmaxf(s[0][r], s[1][r]), fmaxf(s[2][r], s[3][r]));
        #pragma unroll
        for (int off = 1; off < 16; off <<= 1)
            #pragma unroll
            for (int r = 0; r < 4; ++r)
                tmax[r] = fmaxf(tmax[r], __shfl_xor(tmax[r], off, 64));
        float alpha[4];
        #pragma unroll
        for (int r = 0; r < 4; ++r) {
            float mnew = fmaxf(mrun[r], tmax[r]);
            alpha[r] = expf(mrun[r] - mnew);
            mrun[r] = mnew;
        }
        // ---- p = exp(s-m), tile row-sum ----
        float tsum[4] = {0.f, 0.f, 0.f, 0.f};
        #pragma unroll
        for (int fn = 0; fn < 4; ++fn)
            #pragma unroll
            for (int r = 0; r < 4; ++r) {
                float p = expf(s[fn][r] - mrun[r]);
                s[fn][r] = p;
                tsum[r] += p;
            }
        #pragma unroll
        for (int off = 1; off < 16; off <<= 1)
            #pragma unroll
            for (int r = 0; r < 4; ++r)
                tsum[r] += __shfl_xor(tsum[r], off, 64);
        #pragma unroll
        for (int r = 0; r < 4; ++r)
            lrun[r] = lrun[r] * alpha[r] + tsum[r];
        #pragma unroll
        for (int fn = 0; fn < 4; ++fn)
            #pragma unroll
            for (int r = 0; r < 4; ++r)
                o[fn][r] *= alpha[r];
        // ---- P -> bf16 -> LDS (C-layout -> A-layout) ----
        __syncthreads();   // prior iteration's reads finished
        #pragma unroll
        for (int fn = 0; fn < 4; ++fn)
            #pragma unroll
            for (int r = 0; r < 4; ++r)
                plds[wave][lg*4 + r][fn*16 + lr] = __float2bfloat16(s[fn][r]);
        __syncthreads();   // writes visible
        bf16x8 pf[2];
        #pragma unroll
        for (int kk = 0; kk < 2; ++kk)
            pf[kk] = *reinterpret_cast<const bf16x8*>(&plds[wave][lr][kk*32 + lg*8]);
        // ---- O += P V ----
        #pragma unroll
        for (int fn = 0; fn < 4; ++fn) {
            #pragma unroll
            for (int kk = 0; kk < 2; ++kk) {
                bf16x8 vb = *reinterpret_cast<const bf16x8*>(
                    &Vh[(size_t)(fn*16 + lr) * TSEQ + kt*64 + kk*32 + lg*8]);
                o[fn] = __builtin_amdgcn_mfma_f32_16x16x32_bf16(pf[kk], vb, o[fn], 0, 0, 0);
            }
        }
    }
    // ---- epilogue: divide by l, write Y[B,T,H,dk] ----
    int b = bh >> 4, h = bh & 15;
    #pragma unroll
    for (int fn = 0; fn < 4; ++fn)
        #pragma unroll
        for (int r = 0; r < 4; ++r) {
            int t = q0 + lg*4 + r;
            float val = o[fn][r] / lrun[r];
            Y[(((size_t)b * TSEQ + t) * NHEADS + h) * DK + fn*16 + lr] = __float2bfloat16(val);
        }
}

extern "C" void kernel_launch(void* const* d_in, const int* in_sizes, int n_in,
                              void* d_out, int out_size, void* d_ws, size_t ws_size,
                              hipStream_t stream) {
    const float* x  = (const float*)d_in[0];
    const float* wq = (const float*)d_in[1];
    const float* bq = (const float*)d_in[2];
    const float* wk = (const float*)d_in[3];
    const float* bk = (const float*)d_in[4];
    const float* wv = (const float*)d_in[5];
    const float* bv = (const float*)d_in[6];
    const float* wo = (const float*)d_in[7];
    const float* bo = (const float*)d_in[8];
    float* out = (float*)d_out;

    char* ws = (char*)d_ws;
    const size_t MB = 1u << 20;
    bf16_t* xb  = (bf16_t*)(ws);             // 16 MB  (reused as Y after QKV)
    bf16_t* Yb  = (bf16_t*)(ws);             // alias of xb (attention output)
    bf16_t* wqt = (bf16_t*)(ws + 16*MB);     // 2 MB each
    bf16_t* wkt = (bf16_t*)(ws + 18*MB);
    bf16_t* wvt = (bf16_t*)(ws + 20*MB);
    bf16_t* wot = (bf16_t*)(ws + 22*MB);
    bf16_t* Qb  = (bf16_t*)(ws + 24*MB);     // 16 MB
    bf16_t* Kb  = (bf16_t*)(ws + 40*MB);     // 16 MB
    bf16_t* Vtb = (bf16_t*)(ws + 56*MB);     // 16 MB

    const int n4 = (MTOK * D_MODEL) / 4;
    convert_x_kernel<<<(n4 + 255) / 256, 256, 0, stream>>>(x, xb, n4);
    transpose_w_kernel<<<dim3(32, 32, 4), dim3(32, 8), 0, stream>>>(
        wq, wk, wv, wo, wqt, wkt, wvt, wot);

    dim3 ggrid(D_MODEL / 128, MTOK / 128);
    gemm_bf16_kernel<1><<<ggrid, 256, 0, stream>>>(xb, wqt, bq, Qb,  MTOK, D_MODEL, D_MODEL);
    gemm_bf16_kernel<1><<<ggrid, 256, 0, stream>>>(xb, wkt, bk, Kb,  MTOK, D_MODEL, D_MODEL);
    gemm_bf16_kernel<2><<<ggrid, 256, 0, stream>>>(xb, wvt, bv, Vtb, MTOK, D_MODEL, D_MODEL);

    attn_kernel<<<dim3(TSEQ / 64, BATCH * NHEADS), 256, 0, stream>>>(Qb, Kb, Vtb, Yb);

    gemm_bf16_kernel<0><<<ggrid, 256, 0, stream>>>(Yb, wot, bo, out, MTOK, D_MODEL, D_MODEL);
}

// Round 2
// 836.718 us; speedup vs baseline: 1.0129x; 1.0129x over previous
//
#include <hip/hip_runtime.h>
#include <hip/hip_bf16.h>

typedef __attribute__((ext_vector_type(8))) short bf16x8;
typedef __attribute__((ext_vector_type(4))) float f32x4;
typedef __hip_bfloat16 bf16_t;

#define D_MODEL 1024
#define NHEADS  16
#define DK      64
#define TSEQ    2048
#define BATCH   4
#define MTOK    (BATCH*TSEQ)   // 8192

// scale (1/sqrt(dk)) * log2(e), folded into wq/bq so QK^T is in exp2 domain
#define QSCALE 0.18033688011112042f

// ---------------- fp32 -> bf16 elementwise convert (x) ----------------
__global__ __launch_bounds__(256) void convert_x_kernel(const float* __restrict__ x,
                                                        bf16_t* __restrict__ out, int n4) {
    int i = blockIdx.x * 256 + threadIdx.x;
    if (i >= n4) return;
    float4 v = reinterpret_cast<const float4*>(x)[i];
    union { bf16_t h[4]; uint2 u; } p;
    p.h[0] = __float2bfloat16(v.x);
    p.h[1] = __float2bfloat16(v.y);
    p.h[2] = __float2bfloat16(v.z);
    p.h[3] = __float2bfloat16(v.w);
    reinterpret_cast<uint2*>(out)[i] = p.u;
}

// ------------- transpose + convert weights: Wt[n][k] = W[k][n] -------------
__global__ __launch_bounds__(256) void transpose_w_kernel(
    const float* __restrict__ w0, const float* __restrict__ w1,
    const float* __restrict__ w2, const float* __restrict__ w3,
    bf16_t* __restrict__ o0, bf16_t* __restrict__ o1,
    bf16_t* __restrict__ o2, bf16_t* __restrict__ o3) {
    const float* w = (blockIdx.z == 0) ? w0 : (blockIdx.z == 1) ? w1 : (blockIdx.z == 2) ? w2 : w3;
    bf16_t* o = (blockIdx.z == 0) ? o0 : (blockIdx.z == 1) ? o1 : (blockIdx.z == 2) ? o2 : o3;
    const float wscale = (blockIdx.z == 0) ? QSCALE : 1.0f;
    __shared__ float tile[32][33];
    int tx = threadIdx.x, ty = threadIdx.y;     // block (32,8)
    int bx = blockIdx.x * 32;                   // k tile
    int by = blockIdx.y * 32;                   // n tile
    #pragma unroll
    for (int i = 0; i < 4; ++i)
        tile[ty + i*8][tx] = w[(bx + ty + i*8) * D_MODEL + by + tx];
    __syncthreads();
    #pragma unroll
    for (int i = 0; i < 4; ++i)
        o[(by + ty + i*8) * D_MODEL + bx + tx] = __float2bfloat16(tile[tx][ty + i*8] * wscale);
}

// ---------------- GEMM: C[M][N] = A[M][K] * Bt[N][K]^T + bias[n]*bias_scale ----------------
// MODE 0: fp32 plain row-major out
// MODE 1: bf16 out remapped to [B,H,T,dk]   (Q,K)
// MODE 2: bf16 out remapped to [B,H,dk,T]   (V transposed)
template<int MODE>
__global__ __launch_bounds__(256) void gemm_bf16_kernel(
    const bf16_t* __restrict__ A, const bf16_t* __restrict__ Bt,
    const float* __restrict__ bias, void* __restrict__ C,
    int M, int N, int K, float bias_scale) {
    const int tid = threadIdx.x;
    const int wave = tid >> 6, lane = tid & 63;
    const int wm = wave >> 1, wn = wave & 1;          // 2x2 waves -> 128x128 tile
    const int m0 = blockIdx.y * 128 + wm * 64;
    const int n0 = blockIdx.x * 128 + wn * 64;
    const int lr = lane & 15, lg = lane >> 4;

    f32x4 acc[4][4] = {};
    for (int k0 = 0; k0 < K; k0 += 32) {
        bf16x8 a[4], b[4];
        #pragma unroll
        for (int mi = 0; mi < 4; ++mi)
            a[mi] = *reinterpret_cast<const bf16x8*>(&A[(size_t)(m0 + mi*16 + lr) * K + k0 + lg*8]);
        #pragma unroll
        for (int ni = 0; ni < 4; ++ni)
            b[ni] = *reinterpret_cast<const bf16x8*>(&Bt[(size_t)(n0 + ni*16 + lr) * K + k0 + lg*8]);
        #pragma unroll
        for (int mi = 0; mi < 4; ++mi)
            #pragma unroll
            for (int ni = 0; ni < 4; ++ni)
                acc[mi][ni] = __builtin_amdgcn_mfma_f32_16x16x32_bf16(a[mi], b[ni], acc[mi][ni], 0, 0, 0);
    }
    // epilogue
    #pragma unroll
    for (int mi = 0; mi < 4; ++mi) {
        #pragma unroll
        for (int ni = 0; ni < 4; ++ni) {
            int col = n0 + ni*16 + lr;
            float bv = bias[col] * bias_scale;
            #pragma unroll
            for (int r = 0; r < 4; ++r) {
                int row = m0 + mi*16 + lg*4 + r;
                float val = acc[mi][ni][r] + bv;
                if (MODE == 0) {
                    reinterpret_cast<float*>(C)[(size_t)row * N + col] = val;
                } else if (MODE == 1) {
                    size_t idx = (((size_t)(row >> 11) * NHEADS + (col >> 6)) * TSEQ + (row & 2047)) * DK + (col & 63);
                    reinterpret_cast<bf16_t*>(C)[idx] = __float2bfloat16(val);
                } else {
                    size_t idx = (((size_t)(row >> 11) * NHEADS + (col >> 6)) * DK + (col & 63)) * TSEQ + (row & 2047);
                    reinterpret_cast<bf16_t*>(C)[idx] = __float2bfloat16(val);
                }
            }
        }
    }
}

// ---------------- Flash attention (swapped QK^T, all-register, no LDS) ----------------
// Q,K: [BH][T][dk] bf16 ; Vt: [BH][dk][T] bf16 ; Y out: [B][T][H][dk] bf16
// Per wave: 16 q rows. S^T computed via mfma(K_frag, Q_frag): lane holds
// P[q=lane&15][k] for 16 k values. K rows are loaded PERMUTED:
//   row(fk, m) = (fk>>1)*32 + (m>>2)*8 + (fk&1)*4 + (m&3)
// so that each lane's 16 S^T values are exactly its PV A-fragment elements
// (zero cross-lane traffic for P).
__global__ __launch_bounds__(256) void attn_kernel(
    const bf16_t* __restrict__ Q, const bf16_t* __restrict__ K,
    const bf16_t* __restrict__ Vt, bf16_t* __restrict__ Y) {
    const int qb = blockIdx.x;       // q-tile of 64 rows
    const int bh = blockIdx.y;       // b*16+h
    const int tid = threadIdx.x;
    const int wave = tid >> 6, lane = tid & 63;
    const int lr = lane & 15, lg = lane >> 4;
    const int q0 = qb * 64 + wave * 16;          // this wave's 16 q rows

    const bf16_t* Qh = Q + (size_t)bh * TSEQ * DK;
    const bf16_t* Kh = K + (size_t)bh * TSEQ * DK;
    const bf16_t* Vh = Vt + (size_t)bh * DK * TSEQ;

    // Q as B-operand: lane holds Q[q0+lr][kk*32+lg*8 ..]
    bf16x8 qf[2];
    #pragma unroll
    for (int kk = 0; kk < 2; ++kk)
        qf[kk] = *reinterpret_cast<const bf16x8*>(&Qh[(size_t)(q0 + lr) * DK + kk*32 + lg*8]);

    f32x4 o[4] = {};                 // o[fn][r] = O[q0+4*lg+r][fn*16+lr]
    float mrun = -__builtin_inff();  // running max for row q=q0+lr (replicated over lg)
    float lrun = 0.f;                // running sum, same layout

    const int rbase = (lr >> 2) * 8 + (lr & 3);   // permuted K-row base for A-row m=lr
    const int bcast = (lane & 48) | (lg * 4);     // shfl src base: row q=4*lg+r lives at lane (lane&48)|q

    for (int kt = 0; kt <= qb; ++kt) {
        // ---- S^T = K Q^T (already in exp2-scaled domain; wq,bq pre-scaled) ----
        f32x4 s[4] = {};
        #pragma unroll
        for (int fk = 0; fk < 4; ++fk) {
            const int krow = kt*64 + (fk >> 1)*32 + (fk & 1)*4 + rbase;
            #pragma unroll
            for (int kk = 0; kk < 2; ++kk) {
                bf16x8 kbv = *reinterpret_cast<const bf16x8*>(
                    &Kh[(size_t)krow * DK + kk*32 + lg*8]);
                s[fk] = __builtin_amdgcn_mfma_f32_16x16x32_bf16(kbv, qf[kk], s[fk], 0, 0, 0);
            }
        }
        // s[fk][r] holds S^T at k = kt*64 + (fk>>1)*32 + lg*8 + (fk&1)*4 + r, q = q0+lr
        if (kt == qb) {              // causal mask, diagonal tile only
            const int qrow = q0 + lr;
            #pragma unroll
            for (int fk = 0; fk < 4; ++fk) {
                const int kb0 = kt*64 + (fk >> 1)*32 + lg*8 + (fk & 1)*4;
                #pragma unroll
                for (int r = 0; r < 4; ++r)
                    if (kb0 + r > qrow) s[fk][r] = -__builtin_inff();
            }
        }
        // ---- row max: 15 in-lane + 2 cross-group shuffles ----
        float tmax = s[0][0];
        #pragma unroll
        for (int fk = 0; fk < 4; ++fk)
            #pragma unroll
            for (int r = 0; r < 4; ++r)
                tmax = fmaxf(tmax, s[fk][r]);
        tmax = fmaxf(tmax, __shfl_xor(tmax, 16, 64));
        tmax = fmaxf(tmax, __shfl_xor(tmax, 32, 64));

        // ---- defer-max: rescale only when max grew materially (log2 domain) ----
        if (__any(tmax - mrun > 11.5f)) {
            const float mnew = fmaxf(mrun, tmax);
            const float alpha = exp2f(mrun - mnew);
            mrun = mnew;
            lrun *= alpha;
            #pragma unroll
            for (int r = 0; r < 4; ++r) {
                const float ar = __shfl(alpha, bcast + r, 64);
                #pragma unroll
                for (int fn = 0; fn < 4; ++fn)
                    o[fn][r] *= ar;
            }
        }

        // ---- p = 2^(s - m), row sum ----
        float tsum = 0.f;
        #pragma unroll
        for (int fk = 0; fk < 4; ++fk)
            #pragma unroll
            for (int r = 0; r < 4; ++r) {
                const float p = exp2f(s[fk][r] - mrun);
                s[fk][r] = p;
                tsum += p;
            }
        tsum += __shfl_xor(tsum, 16, 64);
        tsum += __shfl_xor(tsum, 32, 64);
        lrun += tsum;

        // ---- pack P to bf16 A-fragments (entirely lane-local thanks to K-row permute) ----
        union { bf16x8 v; bf16_t h[8]; } pa[2];
        #pragma unroll
        for (int c = 0; c < 2; ++c)
            #pragma unroll
            for (int j = 0; j < 8; ++j)
                pa[c].h[j] = __float2bfloat16(s[2*c + (j >> 2)][j & 3]);

        // ---- O += P V ----
        #pragma unroll
        for (int fn = 0; fn < 4; ++fn) {
            #pragma unroll
            for (int c = 0; c < 2; ++c) {
                bf16x8 vb = *reinterpret_cast<const bf16x8*>(
                    &Vh[(size_t)(fn*16 + lr) * TSEQ + kt*64 + c*32 + lg*8]);
                o[fn] = __builtin_amdgcn_mfma_f32_16x16x32_bf16(pa[c].v, vb, o[fn], 0, 0, 0);
            }
        }
    }

    // ---- epilogue: divide by row sum, write Y[B,T,H,dk] ----
    const int b = bh >> 4, h = bh & 15;
    #pragma unroll
    for (int r = 0; r < 4; ++r) {
        const float lsum = __shfl(lrun, bcast + r, 64);
        const float inv = 1.f / lsum;
        const int t = q0 + lg*4 + r;
        #pragma unroll
        for (int fn = 0; fn < 4; ++fn)
            Y[(((size_t)b * TSEQ + t) * NHEADS + h) * DK + fn*16 + lr] =
                __float2bfloat16(o[fn][r] * inv);
    }
}

extern "C" void kernel_launch(void* const* d_in, const int* in_sizes, int n_in,
                              void* d_out, int out_size, void* d_ws, size_t ws_size,
                              hipStream_t stream) {
    const float* x  = (const float*)d_in[0];
    const float* wq = (const float*)d_in[1];
    const float* bq = (const float*)d_in[2];
    const float* wk = (const float*)d_in[3];
    const float* bk = (const float*)d_in[4];
    const float* wv = (const float*)d_in[5];
    const float* bv = (const float*)d_in[6];
    const float* wo = (const float*)d_in[7];
    const float* bo = (const float*)d_in[8];
    float* out = (float*)d_out;

    char* ws = (char*)d_ws;
    const size_t MB = 1u << 20;
    bf16_t* xb  = (bf16_t*)(ws);             // 16 MB  (reused as Y after QKV)
    bf16_t* Yb  = (bf16_t*)(ws);             // alias of xb (attention output)
    bf16_t* wqt = (bf16_t*)(ws + 16*MB);     // 2 MB each
    bf16_t* wkt = (bf16_t*)(ws + 18*MB);
    bf16_t* wvt = (bf16_t*)(ws + 20*MB);
    bf16_t* wot = (bf16_t*)(ws + 22*MB);
    bf16_t* Qb  = (bf16_t*)(ws + 24*MB);     // 16 MB
    bf16_t* Kb  = (bf16_t*)(ws + 40*MB);     // 16 MB
    bf16_t* Vtb = (bf16_t*)(ws + 56*MB);     // 16 MB

    const int n4 = (MTOK * D_MODEL) / 4;
    convert_x_kernel<<<(n4 + 255) / 256, 256, 0, stream>>>(x, xb, n4);
    transpose_w_kernel<<<dim3(32, 32, 4), dim3(32, 8), 0, stream>>>(
        wq, wk, wv, wo, wqt, wkt, wvt, wot);

    dim3 ggrid(D_MODEL / 128, MTOK / 128);
    gemm_bf16_kernel<1><<<ggrid, 256, 0, stream>>>(xb, wqt, bq, Qb,  MTOK, D_MODEL, D_MODEL, QSCALE);
    gemm_bf16_kernel<1><<<ggrid, 256, 0, stream>>>(xb, wkt, bk, Kb,  MTOK, D_MODEL, D_MODEL, 1.0f);
    gemm_bf16_kernel<2><<<ggrid, 256, 0, stream>>>(xb, wvt, bv, Vtb, MTOK, D_MODEL, D_MODEL, 1.0f);

    attn_kernel<<<dim3(TSEQ / 64, BATCH * NHEADS), 256, 0, stream>>>(Qb, Kb, Vtb, Yb);

    gemm_bf16_kernel<0><<<ggrid, 256, 0, stream>>>(Yb, wot, bo, out, MTOK, D_MODEL, D_MODEL, 1.0f);
}

// Round 3
// 427.052 us; speedup vs baseline: 1.9846x; 1.9593x over previous
//
#include <hip/hip_runtime.h>
#include <hip/hip_bf16.h>
#include <stdint.h>

typedef __attribute__((ext_vector_type(8))) short bf16x8;
typedef __attribute__((ext_vector_type(4))) float f32x4;
typedef __hip_bfloat16 bf16_t;

#define D_MODEL 1024
#define NHEADS  16
#define DK      64
#define TSEQ    2048
#define BATCH   4
#define MTOK    (BATCH*TSEQ)   // 8192

// scale (1/sqrt(dk)) * log2(e), folded into wq/bq so QK^T is in exp2 domain
#define QSCALE 0.18033688011112042f

// LDS slot swizzle: spreads the 16 rows a quarter-wave reads across all 8
// 16B-slots of a 128B row. Involution: slot' = slot ^ FSWZ(row).
#define FSWZ(r) ((((r) & 3)) | ((((r) >> 3) & 1) << 2))

typedef __attribute__((address_space(3))) uint32_t lds_u32;
typedef const __attribute__((address_space(1))) uint32_t glb_u32;

__device__ __forceinline__ void load_lds16(const void* g, void* l) {
    // dest = wave-uniform base + lane*16 (linear); source is per-lane.
    __builtin_amdgcn_global_load_lds((glb_u32*)g, (lds_u32*)l, 16, 0, 0);
}

// ---------------- fp32 -> bf16 elementwise convert (x) ----------------
__global__ __launch_bounds__(256) void convert_x_kernel(const float* __restrict__ x,
                                                        bf16_t* __restrict__ out, int n4) {
    int i = blockIdx.x * 256 + threadIdx.x;
    if (i >= n4) return;
    float4 v = reinterpret_cast<const float4*>(x)[i];
    union { bf16_t h[4]; uint2 u; } p;
    p.h[0] = __float2bfloat16(v.x);
    p.h[1] = __float2bfloat16(v.y);
    p.h[2] = __float2bfloat16(v.z);
    p.h[3] = __float2bfloat16(v.w);
    reinterpret_cast<uint2*>(out)[i] = p.u;
}

// ------------- transpose + convert weights: Wt[n][k] = W[k][n] -------------
__global__ __launch_bounds__(256) void transpose_w_kernel(
    const float* __restrict__ w0, const float* __restrict__ w1,
    const float* __restrict__ w2, const float* __restrict__ w3,
    bf16_t* __restrict__ o0, bf16_t* __restrict__ o1,
    bf16_t* __restrict__ o2, bf16_t* __restrict__ o3) {
    const float* w = (blockIdx.z == 0) ? w0 : (blockIdx.z == 1) ? w1 : (blockIdx.z == 2) ? w2 : w3;
    bf16_t* o = (blockIdx.z == 0) ? o0 : (blockIdx.z == 1) ? o1 : (blockIdx.z == 2) ? o2 : o3;
    const float wscale = (blockIdx.z == 0) ? QSCALE : 1.0f;
    __shared__ float tile[32][33];
    int tx = threadIdx.x, ty = threadIdx.y;     // block (32,8)
    int bx = blockIdx.x * 32;                   // k tile
    int by = blockIdx.y * 32;                   // n tile
    #pragma unroll
    for (int i = 0; i < 4; ++i)
        tile[ty + i*8][tx] = w[(bx + ty + i*8) * D_MODEL + by + tx];
    __syncthreads();
    #pragma unroll
    for (int i = 0; i < 4; ++i)
        o[(by + ty + i*8) * D_MODEL + bx + tx] = __float2bfloat16(tile[tx][ty + i*8] * wscale);
}

// ---------------- GEMM: C[M][N] = A[M][K] * Bt[N][K]^T + bias[n]*bias_scale ----------------
template<int MODE>
__global__ __launch_bounds__(256) void gemm_bf16_kernel(
    const bf16_t* __restrict__ A, const bf16_t* __restrict__ Bt,
    const float* __restrict__ bias, void* __restrict__ C,
    int M, int N, int K, float bias_scale) {
    const int tid = threadIdx.x;
    const int wave = tid >> 6, lane = tid & 63;
    const int wm = wave >> 1, wn = wave & 1;          // 2x2 waves -> 128x128 tile
    const int m0 = blockIdx.y * 128 + wm * 64;
    const int n0 = blockIdx.x * 128 + wn * 64;
    const int lr = lane & 15, lg = lane >> 4;

    f32x4 acc[4][4] = {};
    for (int k0 = 0; k0 < K; k0 += 32) {
        bf16x8 a[4], b[4];
        #pragma unroll
        for (int mi = 0; mi < 4; ++mi)
            a[mi] = *reinterpret_cast<const bf16x8*>(&A[(size_t)(m0 + mi*16 + lr) * K + k0 + lg*8]);
        #pragma unroll
        for (int ni = 0; ni < 4; ++ni)
            b[ni] = *reinterpret_cast<const bf16x8*>(&Bt[(size_t)(n0 + ni*16 + lr) * K + k0 + lg*8]);
        #pragma unroll
        for (int mi = 0; mi < 4; ++mi)
            #pragma unroll
            for (int ni = 0; ni < 4; ++ni)
                acc[mi][ni] = __builtin_amdgcn_mfma_f32_16x16x32_bf16(a[mi], b[ni], acc[mi][ni], 0, 0, 0);
    }
    #pragma unroll
    for (int mi = 0; mi < 4; ++mi) {
        #pragma unroll
        for (int ni = 0; ni < 4; ++ni) {
            int col = n0 + ni*16 + lr;
            float bv = bias[col] * bias_scale;
            #pragma unroll
            for (int r = 0; r < 4; ++r) {
                int row = m0 + mi*16 + lg*4 + r;
                float val = acc[mi][ni][r] + bv;
                if (MODE == 0) {
                    reinterpret_cast<float*>(C)[(size_t)row * N + col] = val;
                } else if (MODE == 1) {
                    size_t idx = (((size_t)(row >> 11) * NHEADS + (col >> 6)) * TSEQ + (row & 2047)) * DK + (col & 63);
                    reinterpret_cast<bf16_t*>(C)[idx] = __float2bfloat16(val);
                } else {
                    size_t idx = (((size_t)(row >> 11) * NHEADS + (col >> 6)) * DK + (col & 63)) * TSEQ + (row & 2047);
                    reinterpret_cast<bf16_t*>(C)[idx] = __float2bfloat16(val);
                }
            }
        }
    }
}

// ---------------- Flash attention, LDS-staged K/V, 8 waves, paired q-tiles ----------------
// Q,K: [BH][T][dk] bf16 ; Vt: [BH][dk][T] bf16 ; Y out: [B][T][H][dk] bf16
// Block: 512 threads = 8 waves, two 128-row q-tiles {j, 15-j} -> 34 kv-steps/block.
// Per kv-step: K-tile (64x64) + V-tile (64x64) staged once into LDS via
// global_load_lds (linear dest, inverse-swizzled source), double-buffered,
// counted vmcnt(2) + raw s_barrier (no vmcnt(0) drain in steady state).
__global__ __launch_bounds__(512) void attn_kernel(
    const bf16_t* __restrict__ Q, const bf16_t* __restrict__ K,
    const bf16_t* __restrict__ Vt, bf16_t* __restrict__ Y) {
    const int qpair = blockIdx.x;    // 0..7
    const int bh = blockIdx.y;       // b*16+h
    const int tid = threadIdx.x;
    const int wave = tid >> 6, lane = tid & 63;
    const int lr = lane & 15, lg = lane >> 4;

    const bf16_t* Qh = Q + (size_t)bh * TSEQ * DK;
    const bf16_t* Kh = K + (size_t)bh * TSEQ * DK;
    const bf16_t* Vh = Vt + (size_t)bh * DK * TSEQ;

    // [buf][ K tile 8KB | V tile 8KB ]
    __shared__ __align__(16) char smem[2][16384];

    // staging geometry: thread tid handles 16B segment (row = tid>>3, seg = tid&7)
    const int srow = tid >> 3;
    const int sslot = (tid & 7) ^ FSWZ(srow);
    const size_t koff = (size_t)srow * DK + sslot * 8;          // + kt*64*DK
    const size_t voff = (size_t)srow * TSEQ + sslot * 8;        // + kt*64

    const int rbase = (lr >> 2) * 8 + (lr & 3);   // permuted K-row base (PV A-frag trick)
    const int bcast = (lane & 48) | (lg * 4);     // shfl src for row q=4*lg+r

    #pragma unroll 1
    for (int tt = 0; tt < 2; ++tt) {
        const int j = tt ? (15 - qpair) : qpair;  // q-tile index (128 rows)
        const int NT = 2 * j + 2;                 // kv steps of 64
        const int q0 = j * 128 + wave * 16;       // this wave's 16 q rows

        bf16x8 qf[2];
        #pragma unroll
        for (int kk = 0; kk < 2; ++kk)
            qf[kk] = *reinterpret_cast<const bf16x8*>(&Qh[(size_t)(q0 + lr) * DK + kk*32 + lg*8]);

        f32x4 o[4] = {};
        float mrun = -__builtin_inff();
        float lrun = 0.f;

        int cur = 0;
        // prologue stage kt=0 into buf0
        load_lds16(Kh + koff, smem[0] + wave * 1024);
        load_lds16(Vh + voff, smem[0] + 8192 + wave * 1024);

        #pragma unroll 1
        for (int kt = 0; kt < NT; ++kt) {
            if (kt + 1 < NT) {
                load_lds16(Kh + (size_t)(kt + 1) * 64 * DK + koff, smem[cur ^ 1] + wave * 1024);
                load_lds16(Vh + (size_t)(kt + 1) * 64 + voff, smem[cur ^ 1] + 8192 + wave * 1024);
                asm volatile("s_waitcnt vmcnt(2)" ::: "memory");
            } else {
                asm volatile("s_waitcnt vmcnt(0)" ::: "memory");
            }
            __builtin_amdgcn_s_barrier();
            __builtin_amdgcn_sched_barrier(0);

            if (kt * 64 <= q0 + 15) {    // wave-tile not fully masked
                const char* kb = smem[cur];
                // ---- S^T = K Q^T ----
                f32x4 s[4] = {};
                #pragma unroll
                for (int fk = 0; fk < 4; ++fk) {
                    const int krow = (fk >> 1)*32 + (fk & 1)*4 + rbase;
                    #pragma unroll
                    for (int kk = 0; kk < 2; ++kk) {
                        const bf16x8 kv = *reinterpret_cast<const bf16x8*>(
                            kb + krow*128 + (((kk*4 + lg) ^ FSWZ(krow)) * 16));
                        s[fk] = __builtin_amdgcn_mfma_f32_16x16x32_bf16(kv, qf[kk], s[fk], 0, 0, 0);
                    }
                }
                // ---- causal mask (diagonal region only) ----
                if (kt * 64 + 63 > q0) {
                    const int qrow = q0 + lr;
                    #pragma unroll
                    for (int fk = 0; fk < 4; ++fk) {
                        const int kb0 = kt*64 + (fk >> 1)*32 + lg*8 + (fk & 1)*4;
                        #pragma unroll
                        for (int r = 0; r < 4; ++r)
                            if (kb0 + r > qrow) s[fk][r] = -__builtin_inff();
                    }
                }
                // ---- row max ----
                float tmax = s[0][0];
                #pragma unroll
                for (int fk = 0; fk < 4; ++fk)
                    #pragma unroll
                    for (int r = 0; r < 4; ++r)
                        tmax = fmaxf(tmax, s[fk][r]);
                tmax = fmaxf(tmax, __shfl_xor(tmax, 16, 64));
                tmax = fmaxf(tmax, __shfl_xor(tmax, 32, 64));
                // ---- defer-max rescale ----
                if (__any(tmax - mrun > 11.5f)) {
                    const float mnew = fmaxf(mrun, tmax);
                    const float alpha = exp2f(mrun - mnew);
                    mrun = mnew;
                    lrun *= alpha;
                    #pragma unroll
                    for (int r = 0; r < 4; ++r) {
                        const float ar = __shfl(alpha, bcast + r, 64);
                        #pragma unroll
                        for (int fn = 0; fn < 4; ++fn)
                            o[fn][r] *= ar;
                    }
                }
                // ---- p = 2^(s-m), row sum ----
                float tsum = 0.f;
                #pragma unroll
                for (int fk = 0; fk < 4; ++fk)
                    #pragma unroll
                    for (int r = 0; r < 4; ++r) {
                        const float p = exp2f(s[fk][r] - mrun);
                        s[fk][r] = p;
                        tsum += p;
                    }
                tsum += __shfl_xor(tsum, 16, 64);
                tsum += __shfl_xor(tsum, 32, 64);
                lrun += tsum;
                // ---- pack P to A-fragments (lane-local) ----
                union { bf16x8 v; bf16_t h[8]; } pa[2];
                #pragma unroll
                for (int c = 0; c < 2; ++c)
                    #pragma unroll
                    for (int jj = 0; jj < 8; ++jj)
                        pa[c].h[jj] = __float2bfloat16(s[2*c + (jj >> 2)][jj & 3]);
                // ---- O += P V ----
                #pragma unroll
                for (int fn = 0; fn < 4; ++fn) {
                    const int vrow = fn*16 + lr;
                    #pragma unroll
                    for (int c = 0; c < 2; ++c) {
                        const bf16x8 vv = *reinterpret_cast<const bf16x8*>(
                            kb + 8192 + vrow*128 + (((c*4 + lg) ^ FSWZ(vrow)) * 16));
                        o[fn] = __builtin_amdgcn_mfma_f32_16x16x32_bf16(pa[c].v, vv, o[fn], 0, 0, 0);
                    }
                }
            }
            __builtin_amdgcn_sched_barrier(0);
            __builtin_amdgcn_s_barrier();
            cur ^= 1;
        }

        // ---- epilogue: divide by row sum, write Y[B,T,H,dk] ----
        const int b = bh >> 4, h = bh & 15;
        #pragma unroll
        for (int r = 0; r < 4; ++r) {
            const float lsum = __shfl(lrun, bcast + r, 64);
            const float inv = 1.f / lsum;
            const int t = q0 + lg*4 + r;
            #pragma unroll
            for (int fn = 0; fn < 4; ++fn)
                Y[(((size_t)b * TSEQ + t) * NHEADS + h) * DK + fn*16 + lr] =
                    __float2bfloat16(o[fn][r] * inv);
        }
    }
}

extern "C" void kernel_launch(void* const* d_in, const int* in_sizes, int n_in,
                              void* d_out, int out_size, void* d_ws, size_t ws_size,
                              hipStream_t stream) {
    const float* x  = (const float*)d_in[0];
    const float* wq = (const float*)d_in[1];
    const float* bq = (const float*)d_in[2];
    const float* wk = (const float*)d_in[3];
    const float* bk = (const float*)d_in[4];
    const float* wv = (const float*)d_in[5];
    const float* bv = (const float*)d_in[6];
    const float* wo = (const float*)d_in[7];
    const float* bo = (const float*)d_in[8];
    float* out = (float*)d_out;

    char* ws = (char*)d_ws;
    const size_t MB = 1u << 20;
    bf16_t* xb  = (bf16_t*)(ws);             // 16 MB  (reused as Y after QKV)
    bf16_t* Yb  = (bf16_t*)(ws);             // alias of xb (attention output)
    bf16_t* wqt = (bf16_t*)(ws + 16*MB);     // 2 MB each
    bf16_t* wkt = (bf16_t*)(ws + 18*MB);
    bf16_t* wvt = (bf16_t*)(ws + 20*MB);
    bf16_t* wot = (bf16_t*)(ws + 22*MB);
    bf16_t* Qb  = (bf16_t*)(ws + 24*MB);     // 16 MB
    bf16_t* Kb  = (bf16_t*)(ws + 40*MB);     // 16 MB
    bf16_t* Vtb = (bf16_t*)(ws + 56*MB);     // 16 MB

    const int n4 = (MTOK * D_MODEL) / 4;
    convert_x_kernel<<<(n4 + 255) / 256, 256, 0, stream>>>(x, xb, n4);
    transpose_w_kernel<<<dim3(32, 32, 4), dim3(32, 8), 0, stream>>>(
        wq, wk, wv, wo, wqt, wkt, wvt, wot);

    dim3 ggrid(D_MODEL / 128, MTOK / 128);
    gemm_bf16_kernel<1><<<ggrid, 256, 0, stream>>>(xb, wqt, bq, Qb,  MTOK, D_MODEL, D_MODEL, QSCALE);
    gemm_bf16_kernel<1><<<ggrid, 256, 0, stream>>>(xb, wkt, bk, Kb,  MTOK, D_MODEL, D_MODEL, 1.0f);
    gemm_bf16_kernel<2><<<ggrid, 256, 0, stream>>>(xb, wvt, bv, Vtb, MTOK, D_MODEL, D_MODEL, 1.0f);

    attn_kernel<<<dim3(8, BATCH * NHEADS), 512, 0, stream>>>(Qb, Kb, Vtb, Yb);

    gemm_bf16_kernel<0><<<ggrid, 256, 0, stream>>>(Yb, wot, bo, out, MTOK, D_MODEL, D_MODEL, 1.0f);
}

// Round 6
// 292.540 us; speedup vs baseline: 2.8972x; 1.4598x over previous
//
#include <hip/hip_runtime.h>
#include <hip/hip_bf16.h>
#include <stdint.h>

typedef __attribute__((ext_vector_type(8))) short bf16x8;
typedef __attribute__((ext_vector_type(4))) float f32x4;
typedef __hip_bfloat16 bf16_t;

#define D_MODEL 1024
#define NHEADS  16
#define DK      64
#define TSEQ    2048
#define BATCH   4
#define MTOK    (BATCH*TSEQ)   // 8192

// scale (1/sqrt(dk)) * log2(e), folded into wq/bq so QK^T is in exp2 domain
#define QSCALE 0.18033688011112042f

// attn LDS slot swizzle (64B rows): involution slot' = slot ^ FSWZ(row)
#define FSWZ(r) ((((r) & 3)) | ((((r) >> 3) & 1) << 2))

typedef __attribute__((address_space(3))) uint32_t lds_u32;
typedef const __attribute__((address_space(1))) uint32_t glb_u32;

__device__ __forceinline__ void load_lds16(const void* g, void* l) {
    // dest = wave-uniform base + lane*16 (linear); source is per-lane.
    __builtin_amdgcn_global_load_lds((glb_u32*)g, (lds_u32*)l, 16, 0, 0);
}

// ---------------- fp32 -> bf16 elementwise convert (x) ----------------
__global__ __launch_bounds__(256) void convert_x_kernel(const float* __restrict__ x,
                                                        bf16_t* __restrict__ out, int n4) {
    int i = blockIdx.x * 256 + threadIdx.x;
    if (i >= n4) return;
    float4 v = reinterpret_cast<const float4*>(x)[i];
    union { bf16_t h[4]; uint2 u; } p;
    p.h[0] = __float2bfloat16(v.x);
    p.h[1] = __float2bfloat16(v.y);
    p.h[2] = __float2bfloat16(v.z);
    p.h[3] = __float2bfloat16(v.w);
    reinterpret_cast<uint2*>(out)[i] = p.u;
}

// ------------- transpose + convert weights: Wt[n][k] = W[k][n] -------------
__global__ __launch_bounds__(256) void transpose_w_kernel(
    const float* __restrict__ w0, const float* __restrict__ w1,
    const float* __restrict__ w2, const float* __restrict__ w3,
    bf16_t* __restrict__ o0, bf16_t* __restrict__ o1,
    bf16_t* __restrict__ o2, bf16_t* __restrict__ o3) {
    const float* w = (blockIdx.z == 0) ? w0 : (blockIdx.z == 1) ? w1 : (blockIdx.z == 2) ? w2 : w3;
    bf16_t* o = (blockIdx.z == 0) ? o0 : (blockIdx.z == 1) ? o1 : (blockIdx.z == 2) ? o2 : o3;
    const float wscale = (blockIdx.z == 0) ? QSCALE : 1.0f;
    __shared__ float tile[32][33];
    int tx = threadIdx.x, ty = threadIdx.y;     // block (32,8)
    int bx = blockIdx.x * 32;                   // k tile
    int by = blockIdx.y * 32;                   // n tile
    #pragma unroll
    for (int i = 0; i < 4; ++i)
        tile[ty + i*8][tx] = w[(bx + ty + i*8) * D_MODEL + by + tx];
    __syncthreads();
    #pragma unroll
    for (int i = 0; i < 4; ++i)
        o[(by + ty + i*8) * D_MODEL + bx + tx] = __float2bfloat16(tile[tx][ty + i*8] * wscale);
}

// ======== Staged GEMM (m97 structure): C = A[M,K] * Bt[N,K]^T + bias ========
// 128x128 tile, BK=64, 4 waves, global_load_lds(16B) staging, single-buffered
// 32KB LDS, 2 syncthreads/K-step. LDS rows are 128B; swizzle slot'=slot^(row&7)
// applied on the GLOBAL SOURCE (linear LDS dest, rule #21) and on ds_read.
// NOTE (round-5 fix): staging sources MUST use the BLOCK tile base (mt/nt),
// not the wave's compute sub-tile origin (m0/n0 include wm/wn*64 — using
// them staged rows outside the tile; absmax 8.77 in round 4/5 bench).
// FINAL=0: z=blockIdx.z in {0,1,2} selects wq/wk/wv -> Q/K/Vt (bf16, remapped)
// FINAL=1: fp32 row-major output (out-projection).
template<int FINAL>
__global__ __launch_bounds__(256) void gemm_staged_kernel(
    const bf16_t* __restrict__ A, const bf16_t* __restrict__ BtBase,
    const float* __restrict__ bias0, const float* __restrict__ bias1,
    const float* __restrict__ bias2, void* __restrict__ Cb) {
    const int K = D_MODEL;
    const int tid = threadIdx.x;
    const int wave = tid >> 6, lane = tid & 63;
    const int wm = wave >> 1, wn = wave & 1;          // 2x2 waves -> 128x128 tile
    const int mt = blockIdx.y * 128;                  // block tile bases (staging)
    const int nt = blockIdx.x * 128;
    const int m0 = mt + wm * 64;                      // wave compute sub-tile
    const int n0 = nt + wn * 64;
    const int z = FINAL ? 0 : blockIdx.z;
    const bf16_t* Bt = BtBase + (size_t)z * (D_MODEL * D_MODEL);
    const float* bias = FINAL ? bias0 : (z == 0 ? bias0 : z == 1 ? bias1 : bias2);
    const float bscale = (!FINAL && z == 0) ? QSCALE : 1.0f;
    const int lr = lane & 15, lg = lane >> 4;

    __shared__ __align__(16) bf16_t Atile[128 * 64];   // 16 KB, swizzled
    __shared__ __align__(16) bf16_t Btile[128 * 64];   // 16 KB

    // staging: thread covers linear LDS offset wave*4096 + i*1024 + lane*16
    //   -> row = wave*32 + i*8 + (lane>>3), physslot = lane&7
    //   content for physslot s at row r comes from logical slot s^(r&7)
    const int srow = wave * 32 + (lane >> 3);          // + i*8
    const int sl = (lane & 7) ^ (lane >> 3);           // logical k-slot (16B units)
    const size_t asrc0 = (size_t)(mt + srow) * K + sl * 8;
    const size_t bsrc0 = (size_t)(nt + srow) * K + sl * 8;

    f32x4 acc[4][4] = {};
    #pragma unroll 1
    for (int k0 = 0; k0 < K; k0 += 64) {
        __syncthreads();                                // prev compute reads done
        #pragma unroll
        for (int i = 0; i < 4; ++i) {
            char* adst = (char*)Atile + wave * 4096 + i * 1024;
            char* bdst = (char*)Btile + wave * 4096 + i * 1024;
            load_lds16(A  + asrc0 + (size_t)i * 8 * K + k0, adst);
            load_lds16(Bt + bsrc0 + (size_t)i * 8 * K + k0, bdst);
        }
        __syncthreads();                                // drains vmcnt(0), staging visible
        #pragma unroll
        for (int kk = 0; kk < 2; ++kk) {
            bf16x8 a[4], b[4];
            #pragma unroll
            for (int mi = 0; mi < 4; ++mi) {
                const int row = wm * 64 + mi * 16 + lr;
                a[mi] = *reinterpret_cast<const bf16x8*>(
                    (const char*)Atile + row * 128 + (((kk * 4 + lg) ^ (lr & 7)) * 16));
            }
            #pragma unroll
            for (int ni = 0; ni < 4; ++ni) {
                const int row = wn * 64 + ni * 16 + lr;
                b[ni] = *reinterpret_cast<const bf16x8*>(
                    (const char*)Btile + row * 128 + (((kk * 4 + lg) ^ (lr & 7)) * 16));
            }
            #pragma unroll
            for (int mi = 0; mi < 4; ++mi)
                #pragma unroll
                for (int ni = 0; ni < 4; ++ni)
                    acc[mi][ni] = __builtin_amdgcn_mfma_f32_16x16x32_bf16(a[mi], b[ni], acc[mi][ni], 0, 0, 0);
        }
    }
    // ---- epilogue ----
    #pragma unroll
    for (int mi = 0; mi < 4; ++mi) {
        #pragma unroll
        for (int ni = 0; ni < 4; ++ni) {
            const int col = n0 + ni * 16 + lr;
            const float bv = bias[col] * bscale;
            #pragma unroll
            for (int r = 0; r < 4; ++r) {
                const int row = m0 + mi * 16 + lg * 4 + r;
                const float val = acc[mi][ni][r] + bv;
                if (FINAL) {
                    reinterpret_cast<float*>(Cb)[(size_t)row * D_MODEL + col] = val;
                } else if (z <= 1) {
                    // [B,H,T,dk]
                    size_t idx = (size_t)z * (MTOK * D_MODEL) +
                        (((size_t)(row >> 11) * NHEADS + (col >> 6)) * TSEQ + (row & 2047)) * DK + (col & 63);
                    reinterpret_cast<bf16_t*>(Cb)[idx] = __float2bfloat16(val);
                } else {
                    // [B,H,dk,T]  (V transposed)
                    size_t idx = (size_t)2 * (MTOK * D_MODEL) +
                        (((size_t)(row >> 11) * NHEADS + (col >> 6)) * DK + (col & 63)) * TSEQ + (row & 2047);
                    reinterpret_cast<bf16_t*>(Cb)[idx] = __float2bfloat16(val);
                }
            }
        }
    }
}

// ---------------- Flash attention, LDS-staged K/V, 8 waves, paired q-tiles ----------------
__global__ __launch_bounds__(512) void attn_kernel(
    const bf16_t* __restrict__ Q, const bf16_t* __restrict__ K,
    const bf16_t* __restrict__ Vt, bf16_t* __restrict__ Y) {
    const int qpair = blockIdx.x;    // 0..7
    const int bh = blockIdx.y;       // b*16+h
    const int tid = threadIdx.x;
    const int wave = tid >> 6, lane = tid & 63;
    const int lr = lane & 15, lg = lane >> 4;

    const bf16_t* Qh = Q + (size_t)bh * TSEQ * DK;
    const bf16_t* Kh = K + (size_t)bh * TSEQ * DK;
    const bf16_t* Vh = Vt + (size_t)bh * DK * TSEQ;

    __shared__ __align__(16) char smem[2][16384];   // [buf][K 8KB | V 8KB]

    const int srow = tid >> 3;
    const int sslot = (tid & 7) ^ FSWZ(srow);
    const size_t koff = (size_t)srow * DK + sslot * 8;
    const size_t voff = (size_t)srow * TSEQ + sslot * 8;

    const int rbase = (lr >> 2) * 8 + (lr & 3);
    const int bcast = (lane & 48) | (lg * 4);

    #pragma unroll 1
    for (int tt = 0; tt < 2; ++tt) {
        const int j = tt ? (15 - qpair) : qpair;
        const int NT = 2 * j + 2;
        const int q0 = j * 128 + wave * 16;

        bf16x8 qf[2];
        #pragma unroll
        for (int kk = 0; kk < 2; ++kk)
            qf[kk] = *reinterpret_cast<const bf16x8*>(&Qh[(size_t)(q0 + lr) * DK + kk*32 + lg*8]);

        f32x4 o[4] = {};
        float mrun = -__builtin_inff();
        float lrun = 0.f;

        int cur = 0;
        load_lds16(Kh + koff, smem[0] + wave * 1024);
        load_lds16(Vh + voff, smem[0] + 8192 + wave * 1024);

        #pragma unroll 1
        for (int kt = 0; kt < NT; ++kt) {
            if (kt + 1 < NT) {
                load_lds16(Kh + (size_t)(kt + 1) * 64 * DK + koff, smem[cur ^ 1] + wave * 1024);
                load_lds16(Vh + (size_t)(kt + 1) * 64 + voff, smem[cur ^ 1] + 8192 + wave * 1024);
                asm volatile("s_waitcnt vmcnt(2)" ::: "memory");
            } else {
                asm volatile("s_waitcnt vmcnt(0)" ::: "memory");
            }
            __builtin_amdgcn_s_barrier();
            __builtin_amdgcn_sched_barrier(0);

            if (kt * 64 <= q0 + 15) {
                const char* kb = smem[cur];
                f32x4 s[4] = {};
                #pragma unroll
                for (int fk = 0; fk < 4; ++fk) {
                    const int krow = (fk >> 1)*32 + (fk & 1)*4 + rbase;
                    #pragma unroll
                    for (int kk = 0; kk < 2; ++kk) {
                        const bf16x8 kv = *reinterpret_cast<const bf16x8*>(
                            kb + krow*128 + (((kk*4 + lg) ^ FSWZ(krow)) * 16));
                        s[fk] = __builtin_amdgcn_mfma_f32_16x16x32_bf16(kv, qf[kk], s[fk], 0, 0, 0);
                    }
                }
                if (kt * 64 + 63 > q0) {
                    const int qrow = q0 + lr;
                    #pragma unroll
                    for (int fk = 0; fk < 4; ++fk) {
                        const int kb0 = kt*64 + (fk >> 1)*32 + lg*8 + (fk & 1)*4;
                        #pragma unroll
                        for (int r = 0; r < 4; ++r)
                            if (kb0 + r > qrow) s[fk][r] = -__builtin_inff();
                    }
                }
                float tmax = s[0][0];
                #pragma unroll
                for (int fk = 0; fk < 4; ++fk)
                    #pragma unroll
                    for (int r = 0; r < 4; ++r)
                        tmax = fmaxf(tmax, s[fk][r]);
                tmax = fmaxf(tmax, __shfl_xor(tmax, 16, 64));
                tmax = fmaxf(tmax, __shfl_xor(tmax, 32, 64));
                if (__any(tmax - mrun > 11.5f)) {
                    const float mnew = fmaxf(mrun, tmax);
                    const float alpha = exp2f(mrun - mnew);
                    mrun = mnew;
                    lrun *= alpha;
                    #pragma unroll
                    for (int r = 0; r < 4; ++r) {
                        const float ar = __shfl(alpha, bcast + r, 64);
                        #pragma unroll
                        for (int fn = 0; fn < 4; ++fn)
                            o[fn][r] *= ar;
                    }
                }
                float tsum = 0.f;
                #pragma unroll
                for (int fk = 0; fk < 4; ++fk)
                    #pragma unroll
                    for (int r = 0; r < 4; ++r) {
                        const float p = exp2f(s[fk][r] - mrun);
                        s[fk][r] = p;
                        tsum += p;
                    }
                tsum += __shfl_xor(tsum, 16, 64);
                tsum += __shfl_xor(tsum, 32, 64);
                lrun += tsum;
                union { bf16x8 v; bf16_t h[8]; } pa[2];
                #pragma unroll
                for (int c = 0; c < 2; ++c)
                    #pragma unroll
                    for (int jj = 0; jj < 8; ++jj)
                        pa[c].h[jj] = __float2bfloat16(s[2*c + (jj >> 2)][jj & 3]);
                #pragma unroll
                for (int fn = 0; fn < 4; ++fn) {
                    const int vrow = fn*16 + lr;
                    #pragma unroll
                    for (int c = 0; c < 2; ++c) {
                        const bf16x8 vv = *reinterpret_cast<const bf16x8*>(
                            kb + 8192 + vrow*128 + (((c*4 + lg) ^ FSWZ(vrow)) * 16));
                        o[fn] = __builtin_amdgcn_mfma_f32_16x16x32_bf16(pa[c].v, vv, o[fn], 0, 0, 0);
                    }
                }
            }
            __builtin_amdgcn_sched_barrier(0);
            __builtin_amdgcn_s_barrier();
            cur ^= 1;
        }

        const int b = bh >> 4, h = bh & 15;
        #pragma unroll
        for (int r = 0; r < 4; ++r) {
            const float lsum = __shfl(lrun, bcast + r, 64);
            const float inv = 1.f / lsum;
            const int t = q0 + lg*4 + r;
            #pragma unroll
            for (int fn = 0; fn < 4; ++fn)
                Y[(((size_t)b * TSEQ + t) * NHEADS + h) * DK + fn*16 + lr] =
                    __float2bfloat16(o[fn][r] * inv);
        }
    }
}

extern "C" void kernel_launch(void* const* d_in, const int* in_sizes, int n_in,
                              void* d_out, int out_size, void* d_ws, size_t ws_size,
                              hipStream_t stream) {
    const float* x  = (const float*)d_in[0];
    const float* wq = (const float*)d_in[1];
    const float* bq = (const float*)d_in[2];
    const float* wk = (const float*)d_in[3];
    const float* bk = (const float*)d_in[4];
    const float* wv = (const float*)d_in[5];
    const float* bv = (const float*)d_in[6];
    const float* wo = (const float*)d_in[7];
    const float* bo = (const float*)d_in[8];
    float* out = (float*)d_out;

    char* ws = (char*)d_ws;
    const size_t MB = 1u << 20;
    bf16_t* xb  = (bf16_t*)(ws);             // 16 MB  (reused as Y after QKV)
    bf16_t* Yb  = (bf16_t*)(ws);             // alias of xb (attention output)
    bf16_t* wqt = (bf16_t*)(ws + 16*MB);     // 2 MB each, contiguous (wq,wk,wv)
    bf16_t* wkt = (bf16_t*)(ws + 18*MB);
    bf16_t* wvt = (bf16_t*)(ws + 20*MB);
    bf16_t* wot = (bf16_t*)(ws + 22*MB);
    bf16_t* Qb  = (bf16_t*)(ws + 24*MB);     // 16 MB each, contiguous (Q,K,Vt)
    bf16_t* Kb  = (bf16_t*)(ws + 40*MB);
    bf16_t* Vtb = (bf16_t*)(ws + 56*MB);

    const int n4 = (MTOK * D_MODEL) / 4;
    convert_x_kernel<<<(n4 + 255) / 256, 256, 0, stream>>>(x, xb, n4);
    transpose_w_kernel<<<dim3(32, 32, 4), dim3(32, 8), 0, stream>>>(
        wq, wk, wv, wo, wqt, wkt, wvt, wot);

    // fused QKV projection: z in {0,1,2} -> Q,K,Vt
    gemm_staged_kernel<0><<<dim3(D_MODEL / 128, MTOK / 128, 3), 256, 0, stream>>>(
        xb, wqt, bq, bk, bv, Qb);

    attn_kernel<<<dim3(8, BATCH * NHEADS), 512, 0, stream>>>(Qb, Kb, Vtb, Yb);

    // out projection (fp32 output)
    gemm_staged_kernel<1><<<dim3(D_MODEL / 128, MTOK / 128, 1), 256, 0, stream>>>(
        Yb, wot, bo, nullptr, nullptr, out);
}

// Round 7
// 274.122 us; speedup vs baseline: 3.0918x; 1.0672x over previous
//
#include <hip/hip_runtime.h>
#include <hip/hip_bf16.h>
#include <stdint.h>

typedef __attribute__((ext_vector_type(8))) short bf16x8;
typedef __attribute__((ext_vector_type(4))) float f32x4;
typedef __hip_bfloat16 bf16_t;

#define D_MODEL 1024
#define NHEADS  16
#define DK      64
#define TSEQ    2048
#define BATCH   4
#define MTOK    (BATCH*TSEQ)   // 8192

// scale (1/sqrt(dk)) * log2(e), folded into wq/bq so QK^T is in exp2 domain
#define QSCALE 0.18033688011112042f

// attn LDS slot swizzle (64B rows): involution slot' = slot ^ FSWZ(row)
#define FSWZ(r) ((((r) & 3)) | ((((r) >> 3) & 1) << 2))

typedef __attribute__((address_space(3))) uint32_t lds_u32;
typedef const __attribute__((address_space(1))) uint32_t glb_u32;

__device__ __forceinline__ void load_lds16(const void* g, void* l) {
    // dest = wave-uniform base + lane*16 (linear); source is per-lane.
    __builtin_amdgcn_global_load_lds((glb_u32*)g, (lds_u32*)l, 16, 0, 0);
}

// ---------------- fp32 -> bf16 elementwise convert (x) ----------------
__global__ __launch_bounds__(256) void convert_x_kernel(const float* __restrict__ x,
                                                        bf16_t* __restrict__ out, int n4) {
    int i = blockIdx.x * 256 + threadIdx.x;
    if (i >= n4) return;
    float4 v = reinterpret_cast<const float4*>(x)[i];
    union { bf16_t h[4]; uint2 u; } p;
    p.h[0] = __float2bfloat16(v.x);
    p.h[1] = __float2bfloat16(v.y);
    p.h[2] = __float2bfloat16(v.z);
    p.h[3] = __float2bfloat16(v.w);
    reinterpret_cast<uint2*>(out)[i] = p.u;
}

// ------------- transpose + convert weights: Wt[n][k] = W[k][n] -------------
__global__ __launch_bounds__(256) void transpose_w_kernel(
    const float* __restrict__ w0, const float* __restrict__ w1,
    const float* __restrict__ w2, const float* __restrict__ w3,
    bf16_t* __restrict__ o0, bf16_t* __restrict__ o1,
    bf16_t* __restrict__ o2, bf16_t* __restrict__ o3) {
    const float* w = (blockIdx.z == 0) ? w0 : (blockIdx.z == 1) ? w1 : (blockIdx.z == 2) ? w2 : w3;
    bf16_t* o = (blockIdx.z == 0) ? o0 : (blockIdx.z == 1) ? o1 : (blockIdx.z == 2) ? o2 : o3;
    const float wscale = (blockIdx.z == 0) ? QSCALE : 1.0f;
    __shared__ float tile[32][33];
    int tx = threadIdx.x, ty = threadIdx.y;     // block (32,8)
    int bx = blockIdx.x * 32;                   // k tile
    int by = blockIdx.y * 32;                   // n tile
    #pragma unroll
    for (int i = 0; i < 4; ++i)
        tile[ty + i*8][tx] = w[(bx + ty + i*8) * D_MODEL + by + tx];
    __syncthreads();
    #pragma unroll
    for (int i = 0; i < 4; ++i)
        o[(by + ty + i*8) * D_MODEL + bx + tx] = __float2bfloat16(tile[tx][ty + i*8] * wscale);
}

// ======== Staged GEMM, double-buffered pipeline: C = A[M,K]*Bt[N,K]^T + bias ========
// 128x128 tile, BK=64, 4 waves. global_load_lds(16B) staging into 2 buffers:
// tile k+1's 8 loads issue during tile k's compute; counted s_waitcnt vmcnt(8)
// (never 0 in steady state) + raw s_barrier. LDS 64 KB -> 2 blocks/CU.
// Swizzle slot'=slot^(row&7) on GLOBAL SOURCE + ds_read (rule #21; round-6 verified).
// XCD-aware block swizzle: flat%8 -> XCD; within XCD x fastest, then y, then z,
// so the 8 N-blocks sharing an A-panel hit one XCD's L2 (T1).
// FINAL=0: z in {0,1,2} selects wq/wk/wv -> Q/K/Vt (bf16, remapped)
// FINAL=1: fp32 row-major output (out-projection).
template<int FINAL>
__global__ __launch_bounds__(256) void gemm_staged_kernel(
    const bf16_t* __restrict__ A, const bf16_t* __restrict__ BtBase,
    const float* __restrict__ bias0, const float* __restrict__ bias1,
    const float* __restrict__ bias2, void* __restrict__ Cb) {
    const int K = D_MODEL;
    const int tid = threadIdx.x;
    const int wave = tid >> 6, lane = tid & 63;
    const int wm = wave >> 1, wn = wave & 1;          // 2x2 waves -> 128x128 tile

    // ---- bijective XCD swizzle (gridDim = (8, 64, z)) ----
    const int flat = blockIdx.x + 8 * (blockIdx.y + 64 * blockIdx.z);
    const int xcd = flat & 7;
    const int idx = flat >> 3;
    const int bx  = idx & 7;            // N-tile, fastest within XCD
    const int byl = (idx >> 3) & 7;     // 8 M-panels per XCD
    const int z   = FINAL ? 0 : (idx >> 6);
    const int by  = xcd * 8 + byl;

    const int mt = by * 128;                          // block tile bases (staging)
    const int nt = bx * 128;
    const int m0 = mt + wm * 64;                      // wave compute sub-tile
    const int n0 = nt + wn * 64;
    const bf16_t* Bt = BtBase + (size_t)z * (D_MODEL * D_MODEL);
    const float* bias = FINAL ? bias0 : (z == 0 ? bias0 : z == 1 ? bias1 : bias2);
    const float bscale = (!FINAL && z == 0) ? QSCALE : 1.0f;
    const int lr = lane & 15, lg = lane >> 4;

    __shared__ __align__(16) bf16_t Atile[2][128 * 64];   // 16 KB each, swizzled
    __shared__ __align__(16) bf16_t Btile[2][128 * 64];

    // staging: thread covers linear LDS offset wave*4096 + i*1024 + lane*16
    //   -> row = wave*32 + i*8 + (lane>>3), physslot = lane&7
    //   content for physslot s at row r comes from logical slot s^(r&7)
    const int srow = wave * 32 + (lane >> 3);          // + i*8
    const int sl = (lane & 7) ^ (lane >> 3);           // logical k-slot (16B units)
    const size_t asrc0 = (size_t)(mt + srow) * K + sl * 8;
    const size_t bsrc0 = (size_t)(nt + srow) * K + sl * 8;

    f32x4 acc[4][4] = {};
    int cur = 0;
    // prologue: stage K-tile 0 into buffer 0 (8 loads/wave)
    #pragma unroll
    for (int i = 0; i < 4; ++i) {
        load_lds16(A  + asrc0 + (size_t)i * 8 * K, (char*)Atile[0] + wave * 4096 + i * 1024);
        load_lds16(Bt + bsrc0 + (size_t)i * 8 * K, (char*)Btile[0] + wave * 4096 + i * 1024);
    }

    #pragma unroll 1
    for (int k0 = 0; k0 < K; k0 += 64) {
        if (k0 + 64 < K) {
            // stage next tile into the other buffer while computing this one
            #pragma unroll
            for (int i = 0; i < 4; ++i) {
                load_lds16(A  + asrc0 + (size_t)i * 8 * K + k0 + 64,
                           (char*)Atile[cur ^ 1] + wave * 4096 + i * 1024);
                load_lds16(Bt + bsrc0 + (size_t)i * 8 * K + k0 + 64,
                           (char*)Btile[cur ^ 1] + wave * 4096 + i * 1024);
            }
            asm volatile("s_waitcnt vmcnt(8)" ::: "memory");   // this tile's 8 done
        } else {
            asm volatile("s_waitcnt vmcnt(0)" ::: "memory");
        }
        __builtin_amdgcn_s_barrier();
        __builtin_amdgcn_sched_barrier(0);

        #pragma unroll
        for (int kk = 0; kk < 2; ++kk) {
            bf16x8 a[4], b[4];
            #pragma unroll
            for (int mi = 0; mi < 4; ++mi) {
                const int row = wm * 64 + mi * 16 + lr;
                a[mi] = *reinterpret_cast<const bf16x8*>(
                    (const char*)Atile[cur] + row * 128 + (((kk * 4 + lg) ^ (lr & 7)) * 16));
            }
            #pragma unroll
            for (int ni = 0; ni < 4; ++ni) {
                const int row = wn * 64 + ni * 16 + lr;
                b[ni] = *reinterpret_cast<const bf16x8*>(
                    (const char*)Btile[cur] + row * 128 + (((kk * 4 + lg) ^ (lr & 7)) * 16));
            }
            #pragma unroll
            for (int mi = 0; mi < 4; ++mi)
                #pragma unroll
                for (int ni = 0; ni < 4; ++ni)
                    acc[mi][ni] = __builtin_amdgcn_mfma_f32_16x16x32_bf16(a[mi], b[ni], acc[mi][ni], 0, 0, 0);
        }
        __builtin_amdgcn_sched_barrier(0);
        __builtin_amdgcn_s_barrier();   // all waves done reading buf[cur] before overwrite
        cur ^= 1;
    }
    // ---- epilogue ----
    #pragma unroll
    for (int mi = 0; mi < 4; ++mi) {
        #pragma unroll
        for (int ni = 0; ni < 4; ++ni) {
            const int col = n0 + ni * 16 + lr;
            const float bv = bias[col] * bscale;
            #pragma unroll
            for (int r = 0; r < 4; ++r) {
                const int row = m0 + mi * 16 + lg * 4 + r;
                const float val = acc[mi][ni][r] + bv;
                if (FINAL) {
                    reinterpret_cast<float*>(Cb)[(size_t)row * D_MODEL + col] = val;
                } else if (z <= 1) {
                    // [B,H,T,dk]
                    size_t idx2 = (size_t)z * (MTOK * D_MODEL) +
                        (((size_t)(row >> 11) * NHEADS + (col >> 6)) * TSEQ + (row & 2047)) * DK + (col & 63);
                    reinterpret_cast<bf16_t*>(Cb)[idx2] = __float2bfloat16(val);
                } else {
                    // [B,H,dk,T]  (V transposed)
                    size_t idx2 = (size_t)2 * (MTOK * D_MODEL) +
                        (((size_t)(row >> 11) * NHEADS + (col >> 6)) * DK + (col & 63)) * TSEQ + (row & 2047);
                    reinterpret_cast<bf16_t*>(Cb)[idx2] = __float2bfloat16(val);
                }
            }
        }
    }
}

// ---------------- Flash attention, LDS-staged K/V, 8 waves, paired q-tiles ----------------
__global__ __launch_bounds__(512) void attn_kernel(
    const bf16_t* __restrict__ Q, const bf16_t* __restrict__ K,
    const bf16_t* __restrict__ Vt, bf16_t* __restrict__ Y) {
    const int qpair = blockIdx.x;    // 0..7
    const int bh = blockIdx.y;       // b*16+h
    const int tid = threadIdx.x;
    const int wave = tid >> 6, lane = tid & 63;
    const int lr = lane & 15, lg = lane >> 4;

    const bf16_t* Qh = Q + (size_t)bh * TSEQ * DK;
    const bf16_t* Kh = K + (size_t)bh * TSEQ * DK;
    const bf16_t* Vh = Vt + (size_t)bh * DK * TSEQ;

    __shared__ __align__(16) char smem[2][16384];   // [buf][K 8KB | V 8KB]

    const int srow = tid >> 3;
    const int sslot = (tid & 7) ^ FSWZ(srow);
    const size_t koff = (size_t)srow * DK + sslot * 8;
    const size_t voff = (size_t)srow * TSEQ + sslot * 8;

    const int rbase = (lr >> 2) * 8 + (lr & 3);
    const int bcast = (lane & 48) | (lg * 4);

    #pragma unroll 1
    for (int tt = 0; tt < 2; ++tt) {
        const int j = tt ? (15 - qpair) : qpair;
        const int NT = 2 * j + 2;
        const int q0 = j * 128 + wave * 16;

        bf16x8 qf[2];
        #pragma unroll
        for (int kk = 0; kk < 2; ++kk)
            qf[kk] = *reinterpret_cast<const bf16x8*>(&Qh[(size_t)(q0 + lr) * DK + kk*32 + lg*8]);

        f32x4 o[4] = {};
        float mrun = -__builtin_inff();
        float lrun = 0.f;

        int cur = 0;
        load_lds16(Kh + koff, smem[0] + wave * 1024);
        load_lds16(Vh + voff, smem[0] + 8192 + wave * 1024);

        #pragma unroll 1
        for (int kt = 0; kt < NT; ++kt) {
            if (kt + 1 < NT) {
                load_lds16(Kh + (size_t)(kt + 1) * 64 * DK + koff, smem[cur ^ 1] + wave * 1024);
                load_lds16(Vh + (size_t)(kt + 1) * 64 + voff, smem[cur ^ 1] + 8192 + wave * 1024);
                asm volatile("s_waitcnt vmcnt(2)" ::: "memory");
            } else {
                asm volatile("s_waitcnt vmcnt(0)" ::: "memory");
            }
            __builtin_amdgcn_s_barrier();
            __builtin_amdgcn_sched_barrier(0);

            if (kt * 64 <= q0 + 15) {
                const char* kb = smem[cur];
                f32x4 s[4] = {};
                #pragma unroll
                for (int fk = 0; fk < 4; ++fk) {
                    const int krow = (fk >> 1)*32 + (fk & 1)*4 + rbase;
                    #pragma unroll
                    for (int kk = 0; kk < 2; ++kk) {
                        const bf16x8 kv = *reinterpret_cast<const bf16x8*>(
                            kb + krow*128 + (((kk*4 + lg) ^ FSWZ(krow)) * 16));
                        s[fk] = __builtin_amdgcn_mfma_f32_16x16x32_bf16(kv, qf[kk], s[fk], 0, 0, 0);
                    }
                }
                if (kt * 64 + 63 > q0) {
                    const int qrow = q0 + lr;
                    #pragma unroll
                    for (int fk = 0; fk < 4; ++fk) {
                        const int kb0 = kt*64 + (fk >> 1)*32 + lg*8 + (fk & 1)*4;
                        #pragma unroll
                        for (int r = 0; r < 4; ++r)
                            if (kb0 + r > qrow) s[fk][r] = -__builtin_inff();
                    }
                }
                float tmax = s[0][0];
                #pragma unroll
                for (int fk = 0; fk < 4; ++fk)
                    #pragma unroll
                    for (int r = 0; r < 4; ++r)
                        tmax = fmaxf(tmax, s[fk][r]);
                tmax = fmaxf(tmax, __shfl_xor(tmax, 16, 64));
                tmax = fmaxf(tmax, __shfl_xor(tmax, 32, 64));
                if (__any(tmax - mrun > 11.5f)) {
                    const float mnew = fmaxf(mrun, tmax);
                    const float alpha = exp2f(mrun - mnew);
                    mrun = mnew;
                    lrun *= alpha;
                    #pragma unroll
                    for (int r = 0; r < 4; ++r) {
                        const float ar = __shfl(alpha, bcast + r, 64);
                        #pragma unroll
                        for (int fn = 0; fn < 4; ++fn)
                            o[fn][r] *= ar;
                    }
                }
                float tsum = 0.f;
                #pragma unroll
                for (int fk = 0; fk < 4; ++fk)
                    #pragma unroll
                    for (int r = 0; r < 4; ++r) {
                        const float p = exp2f(s[fk][r] - mrun);
                        s[fk][r] = p;
                        tsum += p;
                    }
                tsum += __shfl_xor(tsum, 16, 64);
                tsum += __shfl_xor(tsum, 32, 64);
                lrun += tsum;
                union { bf16x8 v; bf16_t h[8]; } pa[2];
                #pragma unroll
                for (int c = 0; c < 2; ++c)
                    #pragma unroll
                    for (int jj = 0; jj < 8; ++jj)
                        pa[c].h[jj] = __float2bfloat16(s[2*c + (jj >> 2)][jj & 3]);
                #pragma unroll
                for (int fn = 0; fn < 4; ++fn) {
                    const int vrow = fn*16 + lr;
                    #pragma unroll
                    for (int c = 0; c < 2; ++c) {
                        const bf16x8 vv = *reinterpret_cast<const bf16x8*>(
                            kb + 8192 + vrow*128 + (((c*4 + lg) ^ FSWZ(vrow)) * 16));
                        o[fn] = __builtin_amdgcn_mfma_f32_16x16x32_bf16(pa[c].v, vv, o[fn], 0, 0, 0);
                    }
                }
            }
            __builtin_amdgcn_sched_barrier(0);
            __builtin_amdgcn_s_barrier();
            cur ^= 1;
        }

        const int b = bh >> 4, h = bh & 15;
        #pragma unroll
        for (int r = 0; r < 4; ++r) {
            const float lsum = __shfl(lrun, bcast + r, 64);
            const float inv = 1.f / lsum;
            const int t = q0 + lg*4 + r;
            #pragma unroll
            for (int fn = 0; fn < 4; ++fn)
                Y[(((size_t)b * TSEQ + t) * NHEADS + h) * DK + fn*16 + lr] =
                    __float2bfloat16(o[fn][r] * inv);
        }
    }
}

extern "C" void kernel_launch(void* const* d_in, const int* in_sizes, int n_in,
                              void* d_out, int out_size, void* d_ws, size_t ws_size,
                              hipStream_t stream) {
    const float* x  = (const float*)d_in[0];
    const float* wq = (const float*)d_in[1];
    const float* bq = (const float*)d_in[2];
    const float* wk = (const float*)d_in[3];
    const float* bk = (const float*)d_in[4];
    const float* wv = (const float*)d_in[5];
    const float* bv = (const float*)d_in[6];
    const float* wo = (const float*)d_in[7];
    const float* bo = (const float*)d_in[8];
    float* out = (float*)d_out;

    char* ws = (char*)d_ws;
    const size_t MB = 1u << 20;
    bf16_t* xb  = (bf16_t*)(ws);             // 16 MB  (reused as Y after QKV)
    bf16_t* Yb  = (bf16_t*)(ws);             // alias of xb (attention output)
    bf16_t* wqt = (bf16_t*)(ws + 16*MB);     // 2 MB each, contiguous (wq,wk,wv)
    bf16_t* wkt = (bf16_t*)(ws + 18*MB);
    bf16_t* wvt = (bf16_t*)(ws + 20*MB);
    bf16_t* wot = (bf16_t*)(ws + 22*MB);
    bf16_t* Qb  = (bf16_t*)(ws + 24*MB);     // 16 MB each, contiguous (Q,K,Vt)
    bf16_t* Kb  = (bf16_t*)(ws + 40*MB);
    bf16_t* Vtb = (bf16_t*)(ws + 56*MB);

    const int n4 = (MTOK * D_MODEL) / 4;
    convert_x_kernel<<<(n4 + 255) / 256, 256, 0, stream>>>(x, xb, n4);
    transpose_w_kernel<<<dim3(32, 32, 4), dim3(32, 8), 0, stream>>>(
        wq, wk, wv, wo, wqt, wkt, wvt, wot);

    // fused QKV projection: z in {0,1,2} -> Q,K,Vt
    gemm_staged_kernel<0><<<dim3(D_MODEL / 128, MTOK / 128, 3), 256, 0, stream>>>(
        xb, wqt, bq, bk, bv, Qb);

    attn_kernel<<<dim3(8, BATCH * NHEADS), 512, 0, stream>>>(Qb, Kb, Vtb, Yb);

    // out projection (fp32 output)
    gemm_staged_kernel<1><<<dim3(D_MODEL / 128, MTOK / 128, 1), 256, 0, stream>>>(
        Yb, wot, bo, nullptr, nullptr, out);
}